// Round 9
// baseline (985.893 us; speedup 1.0000x reference)
//
#include <hip/hip_runtime.h>
#include <math.h>

#define MINF 1e-15f
#define ATMAX (1.0f - 1e-7f)
#define BALLMAX (1.0f - 4e-3f)

typedef __attribute__((ext_vector_type(8))) short bf16x8;
typedef __attribute__((ext_vector_type(4))) float f32x4;

__device__ __forceinline__ float wred64(float v){
    #pragma unroll
    for (int m = 1; m < 64; m <<= 1) v += __shfl_xor(v, m, 64);
    return v;
}
__device__ __forceinline__ float red16(float v){
    #pragma unroll
    for (int m = 1; m < 16; m <<= 1) v += __shfl_xor(v, m, 64);
    return v;
}
__device__ __forceinline__ float fatanh(float x){
    return 0.34657359028f * __log2f(__fdividef(1.f + x, 1.f - x));
}
__device__ __forceinline__ float ftanh(float x){
    const float e = __expf(-2.f * x);
    return __fdividef(1.f - e, 1.f + e);
}
__device__ __forceinline__ unsigned pkbf(float a, float b){
    unsigned ua = __float_as_uint(a); ua += 0x7FFFu + ((ua>>16)&1u);
    unsigned ub = __float_as_uint(b); ub += 0x7FFFu + ((ub>>16)&1u);
    return (ua>>16) | (ub & 0xFFFF0000u);
}
__device__ __forceinline__ unsigned short bf16of(float v){
    unsigned u = __float_as_uint(v); u += 0x7FFFu + ((u>>16)&1u);
    return (unsigned short)(u>>16);
}
__device__ __forceinline__ void g2l16(const void* g, void* l){
    __builtin_amdgcn_global_load_lds(
        (const __attribute__((address_space(1))) unsigned int*)g,
        (__attribute__((address_space(3))) unsigned int*)l, 16, 0, 0);
}

// ws layout (floats): [0,786432) B1 bf16 images, fragment-ordered (4br x 48kt x 16KB)
//                     [786432,790528) W1 colsum partials (4br x 8oct x 128)
//                     [790528,...) W2 bf16 images (4br x 32KB, swizzled)
#define WS_CS 786432
#define WS_W2B 3162112   // byte offset of W2 images

// B1 image per 64-K tile, fragment order: off = (n*2+half)*1024 + hi*256 + l15*16 + e*2.
// Prep grid (57,4): bx<48 image tiles; bx 48..55 colsum oct; bx==56 W2 image.
__global__ __launch_bounds__(256) void k_prep(const float* __restrict__ W1,
                                              const float* __restrict__ W2,
                                              float* __restrict__ ws)
{
    const int br = blockIdx.y;
    const int bx = blockIdx.x;
    const int t  = threadIdx.x;
    if (bx < 48){
        __shared__ unsigned short img[8192];           // 16 KB fragment-ordered bf16
        const int kt = bx;
        const float* src = W1 + (size_t)br*393216 + (size_t)kt*64*128;
        char* ic = (char*)img;
        #pragma unroll
        for (int j=0;j<8;j++){
            const int k  = (t>>5) + 8*j;               // 0..63 within tile
            const int c0 = (t&31)*4;
            const float4 v = *(const float4*)(src + k*128 + c0);
            const float vv[4] = {v.x,v.y,v.z,v.w};
            const int half = k>>5, hiv = (k>>3)&3, e = k&7;
            #pragma unroll
            for (int q=0;q<4;q++){
                const int c = c0 + q;
                const int n = c>>4, l15v = c&15;
                const int off = ((n*2+half)<<10) + (hiv<<8) + (l15v<<4) + (e<<1);
                *(unsigned short*)(ic + off) = bf16of(vv[q]);
            }
        }
        __syncthreads();
        float4* dst = (float4*)((char*)ws + ((size_t)(br*48+kt)<<14));
        const float4* s4 = (const float4*)ic;
        #pragma unroll
        for (int j=0;j<4;j++) dst[t + 256*j] = s4[t + 256*j];
    } else if (bx < 56){
        const int oct = bx - 48;
        const int col = t & 127;
        const int par = t >> 7;
        __shared__ float red[256];
        const float* src = W1 + (size_t)br*393216 + (size_t)(oct*384 + par)*128 + col;
        float s = 0.f;
        for (int i=0;i<192;i++) s += src[i*256];
        red[t] = s;
        __syncthreads();
        if (t < 128) ws[WS_CS + (br*8+oct)*128 + t] = red[t] + red[t+128];
    } else {
        __shared__ unsigned short img2[16384];         // 32 KB swizzled [c][k] bf16
        const float* src = W2 + (size_t)br*16384;
        char* ic = (char*)img2;
        #pragma unroll
        for (int j=0;j<16;j++){
            const int f = t + 256*j;
            const int k = f >> 5;
            const int c0 = (f&31)*4;
            const float4 v = *(const float4*)(src + k*128 + c0);
            const float vv[4] = {v.x,v.y,v.z,v.w};
            #pragma unroll
            for (int e=0;e<4;e++){
                const int c = c0 + e;
                const int off = (c*256 + k*2) ^ ((c&7)<<4);
                *(unsigned short*)(ic + off) = bf16of(vv[e]);
            }
        }
        __syncthreads();
        float4* dst = (float4*)((char*)ws + WS_W2B + (size_t)br*32768);
        const float4* s4 = (const float4*)ic;
        #pragma unroll
        for (int j=0;j<8;j++) dst[t + 256*j] = s4[t + 256*j];
    }
}

// Split-K fused encoder: 112-row blocks, 896 thr = 2 K-groups x 7 waves x 16 rows.
// Group g computes K-tiles [24g, 24g+24) with its own 32KB B dbuf (LDS 64KB ->
// 2 blocks/CU -> 28 waves/CU, 2x the latency hiding of the 224-row design).
// Group 1 deposits acc+stats in LDS; group 0 merges and runs the epilogue
// (standardize-fold + b1 + LN + exact GELU + GEMM2 + b2 + tanh(scale) + expmap0 + projx).
__global__ __launch_bounds__(896,7) void k_enc1(
    const float* __restrict__ x0, const float* __restrict__ x1,
    const float* __restrict__ x2, const float* __restrict__ x3,
    const float* __restrict__ ws, const float* __restrict__ b1,
    const float* __restrict__ ln_g, const float* __restrict__ ln_b,
    const float* __restrict__ b2, const float* __restrict__ es,
    float* __restrict__ zout)
{
    __shared__ char smem[65536];   // [0,32K) g0 B dbuf | [32K,64K) g1 B dbuf; merge+h reuse

    const int t  = threadIdx.x;
    const int br = blockIdx.y;
    const int lane = t & 63, w = t >> 6;     // 14 waves
    const int g  = (w >= 7) ? 1 : 0;         // K-half group
    const int wg = w - g*7;                  // wave within group (0..6)
    const int tg = t - g*448;                // thread within group (0..447)
    const int l15 = lane & 15, hi = lane >> 4;
    const size_t row0 = (size_t)blockIdx.x * 112;
    const float* xs = (br==0)?x0:(br==1)?x1:(br==2)?x2:x3;
    const char* bimg = (const char*)ws + ((size_t)(br*48)<<14);

    const int R = (int)row0 + wg*16 + l15;   // this lane's A row
    const float* ap = xs + (size_t)R*3072 + hi*8;
    const unsigned swz = (unsigned)((l15&7)<<4);
    const int kbase = g*24;

    float psum = 0.f, psq = 0.f;
    f32x4 acc[8];
    #pragma unroll
    for (int n=0;n<8;n++) acc[n] = (f32x4){0.f,0.f,0.f,0.f};

    char* Bb  = smem + g*32768;
    char* B0  = Bb;
    char* B1c = Bb + 16384;

    // 16 KB stage with this group's 448 threads: chunks tg, tg+448, (tg<128) tg+896
    auto stage = [&](char* dst, int kt){
        const char* src = bimg + ((size_t)kt<<14);
        g2l16(src + tg*16,         dst + tg*16);
        g2l16(src + (448+tg)*16,   dst + (448+tg)*16);
        if (tg < 128) g2l16(src + (896+tg)*16, dst + (896+tg)*16);
    };
    auto loadA = [&](f32x4* a, int kt){
        const float* p = ap + kt*64;
        a[0] = *(const f32x4*)(p);
        a[1] = *(const f32x4*)(p+4);
        a[2] = *(const f32x4*)(p+32);
        a[3] = *(const f32x4*)(p+36);
    };
    auto comp = [&](const f32x4* a, const char* bt){
        psum += ((a[0][0]+a[0][1])+(a[0][2]+a[0][3])) + ((a[1][0]+a[1][1])+(a[1][2]+a[1][3]))
              + ((a[2][0]+a[2][1])+(a[2][2]+a[2][3])) + ((a[3][0]+a[3][1])+(a[3][2]+a[3][3]));
        psq  += ((a[0][0]*a[0][0]+a[0][1]*a[0][1])+(a[0][2]*a[0][2]+a[0][3]*a[0][3]))
              + ((a[1][0]*a[1][0]+a[1][1]*a[1][1])+(a[1][2]*a[1][2]+a[1][3]*a[1][3]))
              + ((a[2][0]*a[2][0]+a[2][1]*a[2][1])+(a[2][2]*a[2][2]+a[2][3]*a[2][3]))
              + ((a[3][0]*a[3][0]+a[3][1]*a[3][1])+(a[3][2]*a[3][2]+a[3][3]*a[3][3]));
        union { unsigned u[4]; bf16x8 v; } p0, p1;
        p0.u[0]=pkbf(a[0][0],a[0][1]); p0.u[1]=pkbf(a[0][2],a[0][3]);
        p0.u[2]=pkbf(a[1][0],a[1][1]); p0.u[3]=pkbf(a[1][2],a[1][3]);
        p1.u[0]=pkbf(a[2][0],a[2][1]); p1.u[1]=pkbf(a[2][2],a[2][3]);
        p1.u[2]=pkbf(a[3][0],a[3][1]); p1.u[3]=pkbf(a[3][2],a[3][3]);
        const char* bl = bt + lane*16;
        #pragma unroll
        for (int n=0;n<8;n++){
            bf16x8 b0 = *(const bf16x8*)(bl + n*2048);
            bf16x8 b1f = *(const bf16x8*)(bl + n*2048 + 1024);
            acc[n] = __builtin_amdgcn_mfma_f32_16x16x32_bf16(p0.v, b0,  acc[n], 0,0,0);
            acc[n] = __builtin_amdgcn_mfma_f32_16x16x32_bf16(p1.v, b1f, acc[n], 0,0,0);
        }
    };

    f32x4 aA[4], aB[4];
    stage(B0, kbase); loadA(aA, kbase);
    __syncthreads();
    #pragma unroll 1
    for (int it=0; it<24; it+=2){
        stage(B1c, kbase+it+1); loadA(aB, kbase+it+1);
        comp(aA, B0);
        __syncthreads();
        if (it+2 < 24){ stage(B0, kbase+it+2); loadA(aA, kbase+it+2); }
        comp(aB, B1c);
        __syncthreads();
    }

    // split-K merge: pair region wg at byte wg*9216, per-lane slot 144 B (16B aligned)
    float* mp = (float*)(smem + wg*9216 + lane*144);
    if (g){
        #pragma unroll
        for (int n=0;n<8;n++) *(f32x4*)(mp + n*4) = acc[n];
        mp[32] = psum; mp[33] = psq;
    }
    __syncthreads();
    if (!g){
        #pragma unroll
        for (int n=0;n<8;n++){
            const f32x4 m = *(const f32x4*)(mp + n*4);
            acc[n][0]+=m[0]; acc[n][1]+=m[1]; acc[n][2]+=m[2]; acc[n][3]+=m[3];
        }
        psum += mp[32]; psq += mp[33];

        // row stats (wave-local): reduce over hi groups
        float s1 = psum; s1 += __shfl_xor(s1,16,64); s1 += __shfl_xor(s1,32,64);
        float q1 = psq;  q1 += __shfl_xor(q1,16,64); q1 += __shfl_xor(q1,32,64);
        const float mu_l = s1*(1.0f/3072.0f);
        float var = (q1 - s1*s1*(1.0f/3072.0f))*(1.0f/3071.0f);   // ddof=1
        var = fmaxf(var, 0.f);
        const float isd_l = 1.0f/(sqrtf(var)+1e-6f);

        float cs[8], b1v[8], gv[8], bev[8], b2v[8];
        {
            const float* csb = ws + WS_CS + br*1024;
            #pragma unroll
            for (int n=0;n<8;n++){
                const int c = n*16+l15;
                float sc = 0.f;
                #pragma unroll
                for (int o=0;o<8;o++) sc += csb[o*128 + c];
                cs[n]=sc; b1v[n]=b1[br*128+c]; gv[n]=ln_g[br*128+c];
                bev[n]=ln_b[br*128+c]; b2v[n]=b2[br*128+c];
            }
        }

        // h: fold standardize + b1 + LN + exact GELU; bf16 into this pair's LDS region
        char* hc = smem + wg*9216;
        #pragma unroll
        for (int q=0;q<4;q++){
            const float mu  = __shfl(mu_l,  hi*4+q, 64);
            const float isd = __shfl(isd_l, hi*4+q, 64);
            float h[8], Sh=0.f, Sq=0.f;
            #pragma unroll
            for (int n=0;n<8;n++){
                const float v = (acc[n][q] - mu*cs[n])*isd + b1v[n];
                h[n]=v; Sh+=v; Sq+=v*v;
            }
            Sh = red16(Sh); Sq = red16(Sq);
            const float mean = Sh*(1.0f/128.0f);
            const float vr   = fmaxf(Sq*(1.0f/128.0f) - mean*mean, 0.f);
            const float rstd = rsqrtf(vr + 1e-5f);
            const int rw = hi*4+q;
            const unsigned hswz = (unsigned)((rw&7)<<4);
            #pragma unroll
            for (int n=0;n<8;n++){
                const float hn = (h[n]-mean)*rstd*gv[n] + bev[n];
                const float ge = 0.5f*hn*(1.0f + erff(hn*0.70710678118654752f));
                *(unsigned short*)(hc + ((unsigned)(rw*256 + (n*16+l15)*2) ^ hswz)) = bf16of(ge);
            }
        }

        // GEMM2: z = h @ W2 (bf16 MFMA), W2 frags from pre-swizzled L2-hot image
        bf16x8 a2[4];
        #pragma unroll
        for (int kc=0;kc<4;kc++)
            a2[kc] = *(const bf16x8*)(hc + ((unsigned)(l15*256 + kc*64 + hi*16) ^ swz));

        const char* w2i = (const char*)ws + WS_W2B + (size_t)br*32768;
        f32x4 zr[8];
        #pragma unroll
        for (int n=0;n<8;n++){
            f32x4 c2 = (f32x4){0.f,0.f,0.f,0.f};
            #pragma unroll
            for (int kc=0;kc<4;kc++){
                bf16x8 bb = *(const bf16x8*)(w2i + ((unsigned)((n*16+l15)*256 + kc*64 + hi*16) ^ swz));
                c2 = __builtin_amdgcn_mfma_f32_16x16x32_bf16(a2[kc], bb, c2, 0,0,0);
            }
            zr[n] = c2;
        }

        // b2 + tanh(scale) + expmap0 + projx, store z
        const float sc_ = tanhf(es[0]);
        float nq[4] = {0.f,0.f,0.f,0.f};
        #pragma unroll
        for (int n=0;n<8;n++){
            #pragma unroll
            for (int q=0;q<4;q++){
                const float u = sc_*(zr[n][q] + b2v[n]);
                zr[n][q] = u;
                nq[q] = fmaf(u,u,nq[q]);
            }
        }
        #pragma unroll
        for (int q=0;q<4;q++){
            const float n2 = red16(nq[q]);
            const float nn = fmaxf(sqrtf(n2), MINF);
            const float f = __fdividef(fminf(ftanh(nn), BALLMAX), nn);
            float* orow = zout + ((size_t)br*14336 + row0 + wg*16 + hi*4 + q)*128;
            #pragma unroll
            for (int n=0;n<8;n++)
                orow[n*16+l15] = zr[n][q]*f;
        }
    }
}

// Frechet mean, 10 fixed iterations. 16 lanes/task, 8 dims/lane, 4 tasks/wave.
__global__ __launch_bounds__(256) void k_pool(const float* __restrict__ z, float* __restrict__ out4)
{
    const int t = threadIdx.x;
    const int task = (blockIdx.x<<4) + (t>>4);
    const int s = t & 15;
    const int i = task >> 10, b = task & 1023;
    const float* base = z + ((size_t)i*14336 + (size_t)b*14)*128 + s*8;

    float p[14][8]; float py2[14];
    #pragma unroll
    for (int n=0;n<14;n++){
        const float4 v0 = *(const float4*)(base + n*128);
        const float4 v1 = *(const float4*)(base + n*128 + 4);
        p[n][0]=v0.x; p[n][1]=v0.y; p[n][2]=v0.z; p[n][3]=v0.w;
        p[n][4]=v1.x; p[n][5]=v1.y; p[n][6]=v1.z; p[n][7]=v1.w;
        float q=0.f;
        #pragma unroll
        for (int d=0;d<8;d++) q = fmaf(p[n][d],p[n][d],q);
        py2[n] = red16(q);
    }
    float c[8];
    {
        float g[8];
        #pragma unroll
        for (int d=0;d<8;d++) g[d]=0.f;
        #pragma unroll
        for (int n=0;n<14;n++){
            const float nn = fmaxf(sqrtf(py2[n]), MINF);
            const float f = __fdividef(fatanh(fminf(nn, ATMAX)), nn);
            #pragma unroll
            for (int d=0;d<8;d++) g[d] = fmaf(f, p[n][d], g[d]);
        }
        float g2=0.f;
        #pragma unroll
        for (int d=0;d<8;d++){ g[d] *= (1.f/14.f); g2 = fmaf(g[d],g[d],g2); }
        g2 = red16(g2);
        const float ng = fmaxf(sqrtf(g2), MINF);
        const float f = __fdividef(fminf(ftanh(ng), BALLMAX), ng);
        #pragma unroll
        for (int d=0;d<8;d++) c[d] = f*g[d];
    }
    for (int it=0; it<10; ++it){
        float c2p=0.f;
        #pragma unroll
        for (int d=0;d<8;d++) c2p = fmaf(c[d],c[d],c2p);
        const float cur2 = red16(c2p);
        const float l2i = fmaxf(1.f-cur2, MINF);
        float sacc[8];
        #pragma unroll
        for (int d=0;d<8;d++) sacc[d]=0.f;
        #pragma unroll
        for (int n=0;n<14;n++){
            float dp=0.f;
            #pragma unroll
            for (int d=0;d<8;d++) dp = fmaf(c[d],p[n][d],dp);
            const float xy = -red16(dp);
            const float k1 = 1.f + 2.f*xy + py2[n];
            const float rden = __fdividef(1.f, fmaxf(1.f + 2.f*xy + cur2*py2[n], MINF));
            float wv[8], nw2p=0.f;
            #pragma unroll
            for (int d=0;d<8;d++){
                wv[d] = (l2i*p[n][d] - k1*c[d])*rden;
                nw2p = fmaf(wv[d],wv[d],nw2p);
            }
            const float nw2 = red16(nw2p);
            const float nw = fmaxf(sqrtf(nw2), MINF);
            const float ff = l2i * __fdividef(fatanh(fminf(nw, ATMAX)), nw);
            #pragma unroll
            for (int d=0;d<8;d++) sacc[d] = fmaf(ff, wv[d], sacc[d]);
        }
        float nu2p=0.f;
        #pragma unroll
        for (int d=0;d<8;d++){ sacc[d] *= (0.5f/14.f); nu2p = fmaf(sacc[d],sacc[d],nu2p); }
        const float nu2 = red16(nu2p);
        const float nu = fmaxf(sqrtf(nu2), MINF);
        const float fe = __fdividef(ftanh(__fdividef(nu, l2i)), nu);
        float y[8], y2p=0.f, cydp=0.f;
        #pragma unroll
        for (int d=0;d<8;d++){
            y[d] = fe*sacc[d];
            y2p = fmaf(y[d],y[d],y2p);
            cydp = fmaf(c[d],y[d],cydp);
        }
        const float y2 = red16(y2p);
        const float cyd = red16(cydp);
        const float n1 = 1.f + 2.f*cyd + y2;
        const float n2 = 1.f - cur2;
        const float rdn = __fdividef(1.f, fmaxf(1.f + 2.f*cyd + cur2*y2, MINF));
        float nv[8], pn2p=0.f;
        #pragma unroll
        for (int d=0;d<8;d++){
            nv[d] = (n1*c[d] + n2*y[d])*rdn;
            pn2p = fmaf(nv[d],nv[d],pn2p);
        }
        const float pn2 = red16(pn2p);
        const float pn = fmaxf(sqrtf(pn2), MINF);
        const float sc = (pn > BALLMAX) ? __fdividef(BALLMAX, pn) : 1.f;
        #pragma unroll
        for (int d=0;d<8;d++) c[d] = nv[d]*sc;
    }
    float* st = out4 + (size_t)b*1792 + i*128 + s*8;
    const float4 o0 = {c[0],c[1],c[2],c[3]}, o1 = {c[4],c[5],c[6],c[7]};
    *(float4*)st = o0; *(float4*)(st+4) = o1;
}

// softmax-weighted Mobius fusion + projx + broadcast to [B,14,128].
__global__ __launch_bounds__(256) void k_fuse(const float* __restrict__ fw, float* __restrict__ out4)
{
    const int b    = (blockIdx.x<<2) + (threadIdx.x>>6);
    const int lane = threadIdx.x & 63;
    float* slice = out4 + (size_t)b*1792;
    float2 p[4];
    #pragma unroll
    for (int i=0;i<4;i++) p[i] = *(const float2*)(slice + i*128 + lane*2);
    const float f0=fw[0], f1=fw[1], f2=fw[2], f3=fw[3];
    const float mx = fmaxf(fmaxf(f0,f1), fmaxf(f2,f3));
    const float e0=expf(f0-mx), e1=expf(f1-mx), e2=expf(f2-mx), e3=expf(f3-mx);
    const float iz = 1.f/(e0+e1+e2+e3);
    const float ww[4] = {e0*iz, e1*iz, e2*iz, e3*iz};
    float cx, cy;
    {
        const float n2 = wred64(p[0].x*p[0].x + p[0].y*p[0].y);
        const float n = fmaxf(sqrtf(n2), MINF);
        const float f = __fdividef(ftanh(ww[0]*fatanh(fminf(n, ATMAX))), n);
        cx = f*p[0].x; cy = f*p[0].y;
    }
    #pragma unroll
    for (int i=1;i<4;i++){
        const float n2 = wred64(p[i].x*p[i].x + p[i].y*p[i].y);
        const float n = fmaxf(sqrtf(n2), MINF);
        const float f = __fdividef(ftanh(ww[i]*fatanh(fminf(n, ATMAX))), n);
        const float txv = f*p[i].x, tyv = f*p[i].y;
        const float c2 = wred64(cx*cx+cy*cy);
        const float t2 = wred64(txv*txv+tyv*tyv);
        const float ct = wred64(cx*txv+cy*tyv);
        const float n1 = 1.f+2.f*ct+t2, nk = 1.f-c2;
        const float dn = fmaxf(1.f+2.f*ct+c2*t2, MINF);
        const float rdn = __fdividef(1.f, dn);
        cx = (n1*cx+nk*txv)*rdn; cy = (n1*cy+nk*tyv)*rdn;
    }
    {
        const float n2 = wred64(cx*cx+cy*cy);
        const float n = fmaxf(sqrtf(n2), MINF);
        if (n > BALLMAX){ const float sc=__fdividef(BALLMAX,n); cx*=sc; cy*=sc; }
    }
    const float2 o = make_float2(cx,cy);
    #pragma unroll
    for (int nseg=0; nseg<14; ++nseg)
        *(float2*)(slice + nseg*128 + lane*2) = o;
}

extern "C" void kernel_launch(void* const* d_in, const int* in_sizes, int n_in,
                              void* d_out, int out_size, void* d_ws, size_t ws_size,
                              hipStream_t stream)
{
    const float* x0 = (const float*)d_in[0];
    const float* x1 = (const float*)d_in[1];
    const float* x2 = (const float*)d_in[2];
    const float* x3 = (const float*)d_in[3];
    const float* W1 = (const float*)d_in[4];
    const float* b1 = (const float*)d_in[5];
    const float* lg = (const float*)d_in[6];
    const float* lb = (const float*)d_in[7];
    const float* W2 = (const float*)d_in[8];
    const float* b2 = (const float*)d_in[9];
    const float* es = (const float*)d_in[10];
    const float* fw = (const float*)d_in[11];
    float* out  = (float*)d_out;
    float* out4 = out + (size_t)4*14336*128;
    float* ws   = (float*)d_ws;

    dim3 gp(57, 4);
    k_prep<<<gp, 256, 0, stream>>>(W1, W2, ws);
    dim3 g1(128, 4);
    k_enc1<<<g1, 896, 0, stream>>>(x0,x1,x2,x3,ws,b1,lg,lb,b2,es,out);
    k_pool<<<256, 256, 0, stream>>>(out,out4);
    k_fuse<<<256, 256, 0, stream>>>(fw,out4);
}

// Round 10
// 278.042 us; speedup vs baseline: 3.5458x; 3.5458x over previous
//
#include <hip/hip_runtime.h>
#include <math.h>

#define MINF 1e-15f
#define ATMAX (1.0f - 1e-7f)
#define BALLMAX (1.0f - 4e-3f)

typedef __attribute__((ext_vector_type(8))) short bf16x8;
typedef __attribute__((ext_vector_type(4))) float f32x4;

__device__ __forceinline__ float wred64(float v){
    #pragma unroll
    for (int m = 1; m < 64; m <<= 1) v += __shfl_xor(v, m, 64);
    return v;
}
__device__ __forceinline__ float red16(float v){
    #pragma unroll
    for (int m = 1; m < 16; m <<= 1) v += __shfl_xor(v, m, 64);
    return v;
}
__device__ __forceinline__ float fatanh(float x){
    return 0.34657359028f * __log2f(__fdividef(1.f + x, 1.f - x));
}
__device__ __forceinline__ float ftanh(float x){
    const float e = __expf(-2.f * x);
    return __fdividef(1.f - e, 1.f + e);
}
__device__ __forceinline__ unsigned pkbf(float a, float b){
    unsigned ua = __float_as_uint(a); ua += 0x7FFFu + ((ua>>16)&1u);
    unsigned ub = __float_as_uint(b); ub += 0x7FFFu + ((ub>>16)&1u);
    return (ua>>16) | (ub & 0xFFFF0000u);
}
__device__ __forceinline__ unsigned short bf16of(float v){
    unsigned u = __float_as_uint(v); u += 0x7FFFu + ((u>>16)&1u);
    return (unsigned short)(u>>16);
}
__device__ __forceinline__ void g2l16(const void* g, void* l){
    __builtin_amdgcn_global_load_lds(
        (const __attribute__((address_space(1))) unsigned int*)g,
        (__attribute__((address_space(3))) unsigned int*)l, 16, 0, 0);
}

// ws layout (floats): [0,786432) B1 bf16 images, fragment-ordered (4br x 48kt x 16KB)
//                     [786432,790528) W1 colsum partials (4br x 8oct x 128)
//                     [790528,...) W2 bf16 images (4br x 32KB, swizzled)
#define WS_CS 786432
#define WS_W2B 3162112   // byte offset of W2 images

// B1 image per 64-K tile, fragment order: off = (n*2+half)*1024 + hi*256 + l15*16 + e*2.
// Prep grid (57,4): bx<48 image tiles; bx 48..55 colsum oct; bx==56 W2 image.
__global__ __launch_bounds__(256) void k_prep(const float* __restrict__ W1,
                                              const float* __restrict__ W2,
                                              float* __restrict__ ws)
{
    const int br = blockIdx.y;
    const int bx = blockIdx.x;
    const int t  = threadIdx.x;
    if (bx < 48){
        __shared__ unsigned short img[8192];           // 16 KB fragment-ordered bf16
        const int kt = bx;
        const float* src = W1 + (size_t)br*393216 + (size_t)kt*64*128;
        char* ic = (char*)img;
        #pragma unroll
        for (int j=0;j<8;j++){
            const int k  = (t>>5) + 8*j;               // 0..63 within tile
            const int c0 = (t&31)*4;
            const float4 v = *(const float4*)(src + k*128 + c0);
            const float vv[4] = {v.x,v.y,v.z,v.w};
            const int half = k>>5, hiv = (k>>3)&3, e = k&7;
            #pragma unroll
            for (int q=0;q<4;q++){
                const int c = c0 + q;
                const int n = c>>4, l15v = c&15;
                const int off = ((n*2+half)<<10) + (hiv<<8) + (l15v<<4) + (e<<1);
                *(unsigned short*)(ic + off) = bf16of(vv[q]);
            }
        }
        __syncthreads();
        float4* dst = (float4*)((char*)ws + ((size_t)(br*48+kt)<<14));
        const float4* s4 = (const float4*)ic;
        #pragma unroll
        for (int j=0;j<4;j++) dst[t + 256*j] = s4[t + 256*j];
    } else if (bx < 56){
        const int oct = bx - 48;
        const int col = t & 127;
        const int par = t >> 7;
        __shared__ float red[256];
        const float* src = W1 + (size_t)br*393216 + (size_t)(oct*384 + par)*128 + col;
        float s = 0.f;
        for (int i=0;i<192;i++) s += src[i*256];
        red[t] = s;
        __syncthreads();
        if (t < 128) ws[WS_CS + (br*8+oct)*128 + t] = red[t] + red[t+128];
    } else {
        __shared__ unsigned short img2[16384];         // 32 KB swizzled [c][k] bf16
        const float* src = W2 + (size_t)br*16384;
        char* ic = (char*)img2;
        #pragma unroll
        for (int j=0;j<16;j++){
            const int f = t + 256*j;
            const int k = f >> 5;
            const int c0 = (f&31)*4;
            const float4 v = *(const float4*)(src + k*128 + c0);
            const float vv[4] = {v.x,v.y,v.z,v.w};
            #pragma unroll
            for (int e=0;e<4;e++){
                const int c = c0 + e;
                const int off = (c*256 + k*2) ^ ((c&7)<<4);
                *(unsigned short*)(ic + off) = bf16of(vv[e]);
            }
        }
        __syncthreads();
        float4* dst = (float4*)((char*)ws + WS_W2B + (size_t)br*32768);
        const float4* s4 = (const float4*)ic;
        #pragma unroll
        for (int j=0;j<8;j++) dst[t + 256*j] = s4[t + 256*j];
    }
}

// Split-K fused encoder: 112-row blocks, 896 thr = 2 K-groups x 7 waves x 16 rows.
// Group g computes K-tiles [24g, 24g+24) with its own 32KB B dbuf (LDS 64KB ->
// 2 blocks/CU -> 28 waves/CU). Group 1 deposits acc+stats in LDS; group 0 merges
// and runs the epilogue. launch_bounds (896,4): <=128 VGPR cap, no spill (R9 bug fix).
__global__ __launch_bounds__(896,4) void k_enc1(
    const float* __restrict__ x0, const float* __restrict__ x1,
    const float* __restrict__ x2, const float* __restrict__ x3,
    const float* __restrict__ ws, const float* __restrict__ b1,
    const float* __restrict__ ln_g, const float* __restrict__ ln_b,
    const float* __restrict__ b2, const float* __restrict__ es,
    float* __restrict__ zout)
{
    __shared__ char smem[65536];   // [0,32K) g0 B dbuf | [32K,64K) g1 B dbuf; merge+h reuse

    const int t  = threadIdx.x;
    const int br = blockIdx.y;
    const int lane = t & 63, w = t >> 6;     // 14 waves
    const int g  = (w >= 7) ? 1 : 0;         // K-half group
    const int wg = w - g*7;                  // wave within group (0..6)
    const int tg = t - g*448;                // thread within group (0..447)
    const int l15 = lane & 15, hi = lane >> 4;
    const size_t row0 = (size_t)blockIdx.x * 112;
    const float* xs = (br==0)?x0:(br==1)?x1:(br==2)?x2:x3;
    const char* bimg = (const char*)ws + ((size_t)(br*48)<<14);

    const int R = (int)row0 + wg*16 + l15;   // this lane's A row
    const float* ap = xs + (size_t)R*3072 + hi*8;
    const unsigned swz = (unsigned)((l15&7)<<4);
    const int kbase = g*24;

    float psum = 0.f, psq = 0.f;
    f32x4 acc[8];
    #pragma unroll
    for (int n=0;n<8;n++) acc[n] = (f32x4){0.f,0.f,0.f,0.f};

    char* Bb  = smem + g*32768;
    char* B0  = Bb;
    char* B1c = Bb + 16384;

    // 16 KB stage with this group's 448 threads: chunks tg, tg+448, (tg<128) tg+896
    auto stage = [&](char* dst, int kt){
        const char* src = bimg + ((size_t)kt<<14);
        g2l16(src + tg*16,         dst + tg*16);
        g2l16(src + (448+tg)*16,   dst + (448+tg)*16);
        if (tg < 128) g2l16(src + (896+tg)*16, dst + (896+tg)*16);
    };
    auto loadA = [&](f32x4* a, int kt){
        const float* p = ap + kt*64;
        a[0] = *(const f32x4*)(p);
        a[1] = *(const f32x4*)(p+4);
        a[2] = *(const f32x4*)(p+32);
        a[3] = *(const f32x4*)(p+36);
    };
    auto comp = [&](const f32x4* a, const char* bt){
        psum += ((a[0][0]+a[0][1])+(a[0][2]+a[0][3])) + ((a[1][0]+a[1][1])+(a[1][2]+a[1][3]))
              + ((a[2][0]+a[2][1])+(a[2][2]+a[2][3])) + ((a[3][0]+a[3][1])+(a[3][2]+a[3][3]));
        psq  += ((a[0][0]*a[0][0]+a[0][1]*a[0][1])+(a[0][2]*a[0][2]+a[0][3]*a[0][3]))
              + ((a[1][0]*a[1][0]+a[1][1]*a[1][1])+(a[1][2]*a[1][2]+a[1][3]*a[1][3]))
              + ((a[2][0]*a[2][0]+a[2][1]*a[2][1])+(a[2][2]*a[2][2]+a[2][3]*a[2][3]))
              + ((a[3][0]*a[3][0]+a[3][1]*a[3][1])+(a[3][2]*a[3][2]+a[3][3]*a[3][3]));
        union { unsigned u[4]; bf16x8 v; } p0, p1;
        p0.u[0]=pkbf(a[0][0],a[0][1]); p0.u[1]=pkbf(a[0][2],a[0][3]);
        p0.u[2]=pkbf(a[1][0],a[1][1]); p0.u[3]=pkbf(a[1][2],a[1][3]);
        p1.u[0]=pkbf(a[2][0],a[2][1]); p1.u[1]=pkbf(a[2][2],a[2][3]);
        p1.u[2]=pkbf(a[3][0],a[3][1]); p1.u[3]=pkbf(a[3][2],a[3][3]);
        const char* bl = bt + lane*16;
        #pragma unroll
        for (int n=0;n<8;n++){
            bf16x8 b0 = *(const bf16x8*)(bl + n*2048);
            bf16x8 b1f = *(const bf16x8*)(bl + n*2048 + 1024);
            acc[n] = __builtin_amdgcn_mfma_f32_16x16x32_bf16(p0.v, b0,  acc[n], 0,0,0);
            acc[n] = __builtin_amdgcn_mfma_f32_16x16x32_bf16(p1.v, b1f, acc[n], 0,0,0);
        }
    };

    f32x4 aA[4], aB[4];
    stage(B0, kbase); loadA(aA, kbase);
    __syncthreads();
    #pragma unroll 1
    for (int it=0; it<24; it+=2){
        stage(B1c, kbase+it+1); loadA(aB, kbase+it+1);
        comp(aA, B0);
        __syncthreads();
        if (it+2 < 24){ stage(B0, kbase+it+2); loadA(aA, kbase+it+2); }
        comp(aB, B1c);
        __syncthreads();
    }

    // split-K merge: pair region wg at byte wg*9216, per-lane slot 144 B (16B aligned)
    float* mp = (float*)(smem + wg*9216 + lane*144);
    if (g){
        #pragma unroll
        for (int n=0;n<8;n++) *(f32x4*)(mp + n*4) = acc[n];
        mp[32] = psum; mp[33] = psq;
    }
    __syncthreads();
    if (!g){
        #pragma unroll
        for (int n=0;n<8;n++){
            const f32x4 m = *(const f32x4*)(mp + n*4);
            acc[n][0]+=m[0]; acc[n][1]+=m[1]; acc[n][2]+=m[2]; acc[n][3]+=m[3];
        }
        psum += mp[32]; psq += mp[33];

        // row stats (wave-local): reduce over hi groups
        float s1 = psum; s1 += __shfl_xor(s1,16,64); s1 += __shfl_xor(s1,32,64);
        float q1 = psq;  q1 += __shfl_xor(q1,16,64); q1 += __shfl_xor(q1,32,64);
        const float mu_l = s1*(1.0f/3072.0f);
        float var = (q1 - s1*s1*(1.0f/3072.0f))*(1.0f/3071.0f);   // ddof=1
        var = fmaxf(var, 0.f);
        const float isd_l = 1.0f/(sqrtf(var)+1e-6f);

        float cs[8], b1v[8], gv[8], bev[8], b2v[8];
        {
            const float* csb = ws + WS_CS + br*1024;
            #pragma unroll
            for (int n=0;n<8;n++){
                const int c = n*16+l15;
                float sc = 0.f;
                #pragma unroll
                for (int o=0;o<8;o++) sc += csb[o*128 + c];
                cs[n]=sc; b1v[n]=b1[br*128+c]; gv[n]=ln_g[br*128+c];
                bev[n]=ln_b[br*128+c]; b2v[n]=b2[br*128+c];
            }
        }

        // h: fold standardize + b1 + LN + exact GELU; bf16 into this pair's LDS region
        char* hc = smem + wg*9216;
        #pragma unroll
        for (int q=0;q<4;q++){
            const float mu  = __shfl(mu_l,  hi*4+q, 64);
            const float isd = __shfl(isd_l, hi*4+q, 64);
            float h[8], Sh=0.f, Sq=0.f;
            #pragma unroll
            for (int n=0;n<8;n++){
                const float v = (acc[n][q] - mu*cs[n])*isd + b1v[n];
                h[n]=v; Sh+=v; Sq+=v*v;
            }
            Sh = red16(Sh); Sq = red16(Sq);
            const float mean = Sh*(1.0f/128.0f);
            const float vr   = fmaxf(Sq*(1.0f/128.0f) - mean*mean, 0.f);
            const float rstd = rsqrtf(vr + 1e-5f);
            const int rw = hi*4+q;
            const unsigned hswz = (unsigned)((rw&7)<<4);
            #pragma unroll
            for (int n=0;n<8;n++){
                const float hn = (h[n]-mean)*rstd*gv[n] + bev[n];
                const float ge = 0.5f*hn*(1.0f + erff(hn*0.70710678118654752f));
                *(unsigned short*)(hc + ((unsigned)(rw*256 + (n*16+l15)*2) ^ hswz)) = bf16of(ge);
            }
        }

        // GEMM2: z = h @ W2 (bf16 MFMA), W2 frags from pre-swizzled L2-hot image
        bf16x8 a2[4];
        #pragma unroll
        for (int kc=0;kc<4;kc++)
            a2[kc] = *(const bf16x8*)(hc + ((unsigned)(l15*256 + kc*64 + hi*16) ^ swz));

        const char* w2i = (const char*)ws + WS_W2B + (size_t)br*32768;
        f32x4 zr[8];
        #pragma unroll
        for (int n=0;n<8;n++){
            f32x4 c2 = (f32x4){0.f,0.f,0.f,0.f};
            #pragma unroll
            for (int kc=0;kc<4;kc++){
                bf16x8 bb = *(const bf16x8*)(w2i + ((unsigned)((n*16+l15)*256 + kc*64 + hi*16) ^ swz));
                c2 = __builtin_amdgcn_mfma_f32_16x16x32_bf16(a2[kc], bb, c2, 0,0,0);
            }
            zr[n] = c2;
        }

        // b2 + tanh(scale) + expmap0 + projx, store z
        const float sc_ = tanhf(es[0]);
        float nq[4] = {0.f,0.f,0.f,0.f};
        #pragma unroll
        for (int n=0;n<8;n++){
            #pragma unroll
            for (int q=0;q<4;q++){
                const float u = sc_*(zr[n][q] + b2v[n]);
                zr[n][q] = u;
                nq[q] = fmaf(u,u,nq[q]);
            }
        }
        #pragma unroll
        for (int q=0;q<4;q++){
            const float n2 = red16(nq[q]);
            const float nn = fmaxf(sqrtf(n2), MINF);
            const float f = __fdividef(fminf(ftanh(nn), BALLMAX), nn);
            float* orow = zout + ((size_t)br*14336 + row0 + wg*16 + hi*4 + q)*128;
            #pragma unroll
            for (int n=0;n<8;n++)
                orow[n*16+l15] = zr[n][q]*f;
        }
    }
}

// Frechet mean, 10 fixed iterations. 16 lanes/task, 8 dims/lane, 4 tasks/wave.
__global__ __launch_bounds__(256) void k_pool(const float* __restrict__ z, float* __restrict__ out4)
{
    const int t = threadIdx.x;
    const int task = (blockIdx.x<<4) + (t>>4);
    const int s = t & 15;
    const int i = task >> 10, b = task & 1023;
    const float* base = z + ((size_t)i*14336 + (size_t)b*14)*128 + s*8;

    float p[14][8]; float py2[14];
    #pragma unroll
    for (int n=0;n<14;n++){
        const float4 v0 = *(const float4*)(base + n*128);
        const float4 v1 = *(const float4*)(base + n*128 + 4);
        p[n][0]=v0.x; p[n][1]=v0.y; p[n][2]=v0.z; p[n][3]=v0.w;
        p[n][4]=v1.x; p[n][5]=v1.y; p[n][6]=v1.z; p[n][7]=v1.w;
        float q=0.f;
        #pragma unroll
        for (int d=0;d<8;d++) q = fmaf(p[n][d],p[n][d],q);
        py2[n] = red16(q);
    }
    float c[8];
    {
        float g[8];
        #pragma unroll
        for (int d=0;d<8;d++) g[d]=0.f;
        #pragma unroll
        for (int n=0;n<14;n++){
            const float nn = fmaxf(sqrtf(py2[n]), MINF);
            const float f = __fdividef(fatanh(fminf(nn, ATMAX)), nn);
            #pragma unroll
            for (int d=0;d<8;d++) g[d] = fmaf(f, p[n][d], g[d]);
        }
        float g2=0.f;
        #pragma unroll
        for (int d=0;d<8;d++){ g[d] *= (1.f/14.f); g2 = fmaf(g[d],g[d],g2); }
        g2 = red16(g2);
        const float ng = fmaxf(sqrtf(g2), MINF);
        const float f = __fdividef(fminf(ftanh(ng), BALLMAX), ng);
        #pragma unroll
        for (int d=0;d<8;d++) c[d] = f*g[d];
    }
    for (int it=0; it<10; ++it){
        float c2p=0.f;
        #pragma unroll
        for (int d=0;d<8;d++) c2p = fmaf(c[d],c[d],c2p);
        const float cur2 = red16(c2p);
        const float l2i = fmaxf(1.f-cur2, MINF);
        float sacc[8];
        #pragma unroll
        for (int d=0;d<8;d++) sacc[d]=0.f;
        #pragma unroll
        for (int n=0;n<14;n++){
            float dp=0.f;
            #pragma unroll
            for (int d=0;d<8;d++) dp = fmaf(c[d],p[n][d],dp);
            const float xy = -red16(dp);
            const float k1 = 1.f + 2.f*xy + py2[n];
            const float rden = __fdividef(1.f, fmaxf(1.f + 2.f*xy + cur2*py2[n], MINF));
            float wv[8], nw2p=0.f;
            #pragma unroll
            for (int d=0;d<8;d++){
                wv[d] = (l2i*p[n][d] - k1*c[d])*rden;
                nw2p = fmaf(wv[d],wv[d],nw2p);
            }
            const float nw2 = red16(nw2p);
            const float nw = fmaxf(sqrtf(nw2), MINF);
            const float ff = l2i * __fdividef(fatanh(fminf(nw, ATMAX)), nw);
            #pragma unroll
            for (int d=0;d<8;d++) sacc[d] = fmaf(ff, wv[d], sacc[d]);
        }
        float nu2p=0.f;
        #pragma unroll
        for (int d=0;d<8;d++){ sacc[d] *= (0.5f/14.f); nu2p = fmaf(sacc[d],sacc[d],nu2p); }
        const float nu2 = red16(nu2p);
        const float nu = fmaxf(sqrtf(nu2), MINF);
        const float fe = __fdividef(ftanh(__fdividef(nu, l2i)), nu);
        float y[8], y2p=0.f, cydp=0.f;
        #pragma unroll
        for (int d=0;d<8;d++){
            y[d] = fe*sacc[d];
            y2p = fmaf(y[d],y[d],y2p);
            cydp = fmaf(c[d],y[d],cydp);
        }
        const float y2 = red16(y2p);
        const float cyd = red16(cydp);
        const float n1 = 1.f + 2.f*cyd + y2;
        const float n2 = 1.f - cur2;
        const float rdn = __fdividef(1.f, fmaxf(1.f + 2.f*cyd + cur2*y2, MINF));
        float nv[8], pn2p=0.f;
        #pragma unroll
        for (int d=0;d<8;d++){
            nv[d] = (n1*c[d] + n2*y[d])*rdn;
            pn2p = fmaf(nv[d],nv[d],pn2p);
        }
        const float pn2 = red16(pn2p);
        const float pn = fmaxf(sqrtf(pn2), MINF);
        const float sc = (pn > BALLMAX) ? __fdividef(BALLMAX, pn) : 1.f;
        #pragma unroll
        for (int d=0;d<8;d++) c[d] = nv[d]*sc;
    }
    float* st = out4 + (size_t)b*1792 + i*128 + s*8;
    const float4 o0 = {c[0],c[1],c[2],c[3]}, o1 = {c[4],c[5],c[6],c[7]};
    *(float4*)st = o0; *(float4*)(st+4) = o1;
}

// softmax-weighted Mobius fusion + projx + broadcast to [B,14,128].
__global__ __launch_bounds__(256) void k_fuse(const float* __restrict__ fw, float* __restrict__ out4)
{
    const int b    = (blockIdx.x<<2) + (threadIdx.x>>6);
    const int lane = threadIdx.x & 63;
    float* slice = out4 + (size_t)b*1792;
    float2 p[4];
    #pragma unroll
    for (int i=0;i<4;i++) p[i] = *(const float2*)(slice + i*128 + lane*2);
    const float f0=fw[0], f1=fw[1], f2=fw[2], f3=fw[3];
    const float mx = fmaxf(fmaxf(f0,f1), fmaxf(f2,f3));
    const float e0=expf(f0-mx), e1=expf(f1-mx), e2=expf(f2-mx), e3=expf(f3-mx);
    const float iz = 1.f/(e0+e1+e2+e3);
    const float ww[4] = {e0*iz, e1*iz, e2*iz, e3*iz};
    float cx, cy;
    {
        const float n2 = wred64(p[0].x*p[0].x + p[0].y*p[0].y);
        const float n = fmaxf(sqrtf(n2), MINF);
        const float f = __fdividef(ftanh(ww[0]*fatanh(fminf(n, ATMAX))), n);
        cx = f*p[0].x; cy = f*p[0].y;
    }
    #pragma unroll
    for (int i=1;i<4;i++){
        const float n2 = wred64(p[i].x*p[i].x + p[i].y*p[i].y);
        const float n = fmaxf(sqrtf(n2), MINF);
        const float f = __fdividef(ftanh(ww[i]*fatanh(fminf(n, ATMAX))), n);
        const float txv = f*p[i].x, tyv = f*p[i].y;
        const float c2 = wred64(cx*cx+cy*cy);
        const float t2 = wred64(txv*txv+tyv*tyv);
        const float ct = wred64(cx*txv+cy*tyv);
        const float n1 = 1.f+2.f*ct+t2, nk = 1.f-c2;
        const float dn = fmaxf(1.f+2.f*ct+c2*t2, MINF);
        const float rdn = __fdividef(1.f, dn);
        cx = (n1*cx+nk*txv)*rdn; cy = (n1*cy+nk*tyv)*rdn;
    }
    {
        const float n2 = wred64(cx*cx+cy*cy);
        const float n = fmaxf(sqrtf(n2), MINF);
        if (n > BALLMAX){ const float sc=__fdividef(BALLMAX,n); cx*=sc; cy*=sc; }
    }
    const float2 o = make_float2(cx,cy);
    #pragma unroll
    for (int nseg=0; nseg<14; ++nseg)
        *(float2*)(slice + nseg*128 + lane*2) = o;
}

extern "C" void kernel_launch(void* const* d_in, const int* in_sizes, int n_in,
                              void* d_out, int out_size, void* d_ws, size_t ws_size,
                              hipStream_t stream)
{
    const float* x0 = (const float*)d_in[0];
    const float* x1 = (const float*)d_in[1];
    const float* x2 = (const float*)d_in[2];
    const float* x3 = (const float*)d_in[3];
    const float* W1 = (const float*)d_in[4];
    const float* b1 = (const float*)d_in[5];
    const float* lg = (const float*)d_in[6];
    const float* lb = (const float*)d_in[7];
    const float* W2 = (const float*)d_in[8];
    const float* b2 = (const float*)d_in[9];
    const float* es = (const float*)d_in[10];
    const float* fw = (const float*)d_in[11];
    float* out  = (float*)d_out;
    float* out4 = out + (size_t)4*14336*128;
    float* ws   = (float*)d_ws;

    dim3 gp(57, 4);
    k_prep<<<gp, 256, 0, stream>>>(W1, W2, ws);
    dim3 g1(128, 4);
    k_enc1<<<g1, 896, 0, stream>>>(x0,x1,x2,x3,ws,b1,lg,lb,b2,es,out);
    k_pool<<<256, 256, 0, stream>>>(out,out4);
    k_fuse<<<256, 256, 0, stream>>>(fw,out4);
}